// Round 1
// baseline (783.970 us; speedup 1.0000x reference)
//
#include <hip/hip_runtime.h>
#include <math.h>

#define MF 16384
#define HALF 8192
#define LOG2M 14

__device__ __forceinline__ float2 cmulf(float2 a, float2 b) {
    return make_float2(a.x*b.x - a.y*b.y, a.x*b.y + a.y*b.x);
}
__device__ __forceinline__ int brev14(int x) { return (int)(__brev((unsigned)x) >> 18); }

// ---------------- twiddle table: Tbl[i] = exp(-2*pi*i*j/MF), j in [0, HALF) ----------------
__global__ void k_twiddle(float2* __restrict__ Tbl) {
    int i = blockIdx.x * blockDim.x + threadIdx.x;
    if (i < HALF) {
        double a = -2.0 * 3.14159265358979323846 * (double)i / (double)MF;
        Tbl[i] = make_float2((float)cos(a), (float)sin(a));
    }
}

// ---------------- evaluate generating function: E[d][l] ----------------
__global__ void k_eval(const float2* __restrict__ Lam, const float2* __restrict__ P,
                       const float2* __restrict__ Bc, const float2* __restrict__ C,
                       const float* __restrict__ log_step, float2* __restrict__ E) {
    int gid = blockIdx.x * blockDim.x + threadIdx.x;
    int l = gid & (MF - 1);
    int d = gid >> LOG2M;

    double step = exp((double)log_step[0]);
    double phi = -2.0 * 3.14159265358979323846 * ((double)l / (double)MF);
    double omx = cos(phi), omy = sin(phi);
    double dx = 1.0 + omx, dy = omy;        // 1 + Omega
    double nx = 1.0 - omx, ny = -omy;       // 1 - Omega
    double idd = 1.0 / (dx*dx + dy*dy);
    double rx = (nx*dx + ny*dy) * idd;      // (1-Om)/(1+Om)
    double ry = (ny*dx - nx*dy) * idd;
    double ts = 2.0 / step;
    double gx = ts * rx, gy = ts * ry;

    double k00x=0,k00y=0,k01x=0,k01y=0,k10x=0,k10y=0,k11x=0,k11y=0;
    #pragma unroll 8
    for (int n = 0; n < 64; ++n) {
        float2 ln = Lam[n]; float2 pn = P[n]; float2 bn = Bc[n]; float2 cn = C[d*64 + n];
        double ex = gx - (double)ln.x, ey = gy - (double)ln.y;
        double inv = 1.0 / (ex*ex + ey*ey);
        double cx = ex * inv, cy = -ey * inv;                 // cauchy = 1/(g - Lam)
        double t0x = (double)bn.x*cx - (double)bn.y*cy;       // b0 * cauchy
        double t0y = (double)bn.x*cy + (double)bn.y*cx;
        double t1x = (double)pn.x*cx - (double)pn.y*cy;       // b1 * cauchy
        double t1y = (double)pn.x*cy + (double)pn.y*cx;
        double a0x = (double)cn.x, a0y = -(double)cn.y;       // conj(C)
        double a1x = (double)pn.x, a1y = -(double)pn.y;       // conj(P)
        k00x += a0x*t0x - a0y*t0y;  k00y += a0x*t0y + a0y*t0x;
        k01x += a0x*t1x - a0y*t1y;  k01y += a0x*t1y + a0y*t1x;
        k10x += a1x*t0x - a1y*t0y;  k10y += a1x*t0y + a1y*t0x;
        k11x += a1x*t1x - a1y*t1y;  k11y += a1x*t1y + a1y*t1x;
    }
    // val = k00 - k01 * k10/(1+k11)
    double ux = 1.0 + k11x, uy = k11y;
    double iu = 1.0 / (ux*ux + uy*uy);
    double qx = (k10x*ux + k10y*uy) * iu;
    double qy = (k10y*ux - k10x*uy) * iu;
    double vx = k00x - (k01x*qx - k01y*qy);
    double vy = k00y - (k01x*qy + k01y*qx);
    // pref = 2/(1+Omega)
    double px = 2.0*dx*idd, py = -2.0*dy*idd;
    double ox = px*vx - py*vy, oy = px*vy + py*vx;
    E[(size_t)d*MF + l] = make_float2((float)ox, (float)oy);
}

// ---------------- in-LDS radix-2 FFT core (1024 threads, 16384 points) ----------------
__device__ void fft_dif(float2* A, const float2* __restrict__ Tbl, int tid) {
    __syncthreads();
    for (int h = HALF; h >= 1; h >>= 1) {
        int mult = HALF / h;
        #pragma unroll
        for (int r = 0; r < 8; ++r) {
            int m = tid + r * 1024;
            int j = m & (h - 1);
            int base = ((m ^ j) << 1) | j;
            float2 a = A[base], b = A[base + h];
            float2 tw = Tbl[j * mult];
            float2 df = make_float2(a.x - b.x, a.y - b.y);
            A[base]     = make_float2(a.x + b.x, a.y + b.y);
            A[base + h] = cmulf(df, tw);
        }
        __syncthreads();
    }
}
__device__ void fft_dit_inv(float2* A, const float2* __restrict__ Tbl, int tid) {
    __syncthreads();
    for (int h = 1; h <= HALF; h <<= 1) {
        int mult = HALF / h;
        #pragma unroll
        for (int r = 0; r < 8; ++r) {
            int m = tid + r * 1024;
            int j = m & (h - 1);
            int base = ((m ^ j) << 1) | j;
            float2 a = A[base], b = A[base + h];
            float2 tw = Tbl[j * mult]; tw.y = -tw.y;
            float2 bt = cmulf(b, tw);
            A[base]     = make_float2(a.x + bt.x, a.y + bt.y);
            A[base + h] = make_float2(a.x - bt.x, a.y - bt.y);
        }
        __syncthreads();
    }
}

// ---------------- K time domain: Kt[d][t] = Re(ifft(E[d])) ----------------
__global__ __launch_bounds__(1024) void k_ifft_E(const float2* __restrict__ E, float* __restrict__ Kt,
                                                 const float2* __restrict__ Tbl) {
    __shared__ float2 A[MF];
    int d = blockIdx.x, tid = threadIdx.x;
    const float2* Ed = E + (size_t)d * MF;
    #pragma unroll
    for (int r = 0; r < 16; ++r) { int l = tid + r * 1024; A[brev14(l)] = Ed[l]; }
    fft_dit_inv(A, Tbl, tid);
    const float s = 1.0f / (float)MF;
    float* Ktd = Kt + (size_t)d * MF;
    #pragma unroll
    for (int r = 0; r < 16; ++r) { int t = tid + r * 1024; Ktd[t] = A[t].x * s; }
}

// ---------------- Kd[d][k], k in [0,2*MF): 32768-point real FFT of padded K column ----------------
__global__ __launch_bounds__(1024) void k_fft_K(const float* __restrict__ Kt, float2* __restrict__ Kd,
                                                const float2* __restrict__ Tbl) {
    __shared__ float2 A[MF];
    int d = blockIdx.x, tid = threadIdx.x;
    const float2* src = (const float2*)(Kt + (size_t)d * MF);
    #pragma unroll
    for (int r = 0; r < 16; ++r) {
        int t = tid + r * 1024;
        A[t] = (t < HALF) ? src[t] : make_float2(0.f, 0.f);
    }
    fft_dif(A, Tbl, tid);
    float2* Kdd = Kd + (size_t)d * 2 * MF;
    #pragma unroll
    for (int r = 0; r < 16; ++r) {
        int k = tid + r * 1024;
        float2 Zk = A[brev14(k)];
        float2 Zm = A[brev14((MF - k) & (MF - 1))];
        Zm.y = -Zm.y;
        float2 Ue = make_float2(0.5f*(Zk.x + Zm.x), 0.5f*(Zk.y + Zm.y));
        float2 dd = make_float2(Zk.x - Zm.x, Zk.y - Zm.y);
        float2 Uo = make_float2(0.5f*dd.y, -0.5f*dd.x);
        float kf = (float)k * (1.0f / (float)MF);
        float2 w = make_float2(cospif(kf), -sinpif(kf));
        float2 t2 = cmulf(w, Uo);
        Kdd[k]      = make_float2(Ue.x + t2.x, Ue.y + t2.y);
        Kdd[MF + k] = make_float2(Ue.x - t2.x, Ue.y - t2.y);
    }
}

// ---------------- transpose u (B,L,D) -> uT (B,D,L) ----------------
__global__ void k_transpose_in(const float* __restrict__ u, float* __restrict__ uT) {
    __shared__ float tile[64][65];
    int b = blockIdx.y, t0 = blockIdx.x * 64, tid = threadIdx.x;
    #pragma unroll
    for (int k2 = 0; k2 < 16; ++k2) {
        int idx = tid + k2 * 256;
        int tl = idx >> 6, dl = idx & 63;
        tile[tl][dl] = u[((size_t)(b * MF + t0 + tl)) * 64 + dl];
    }
    __syncthreads();
    #pragma unroll
    for (int k2 = 0; k2 < 16; ++k2) {
        int idx = tid + k2 * 256;
        int dl = idx >> 6, tl = idx & 63;
        uT[((size_t)b * 64 + dl) * MF + t0 + tl] = tile[tl][dl];
    }
}

// ---------------- main conv: per (b,d) one 16384-pt packed-real FFT conv ----------------
template<bool TRANS>
__global__ __launch_bounds__(1024) void k_conv(const float* __restrict__ u, const float* __restrict__ uT,
                                               const float2* __restrict__ Kd, const float* __restrict__ Dp,
                                               float* __restrict__ yT, float* __restrict__ yout,
                                               const float2* __restrict__ Tbl) {
    __shared__ float2 A[MF];
    int bd = blockIdx.x, tid = threadIdx.x;
    int b = bd >> 6, d = bd & 63;
    if (TRANS) {
        const float2* src = (const float2*)(uT + (size_t)bd * MF);
        #pragma unroll
        for (int r = 0; r < 16; ++r) { int t = tid + r * 1024; A[t] = (t < HALF) ? src[t] : make_float2(0.f, 0.f); }
    } else {
        const float* ub = u + ((size_t)b * MF) * 64 + d;
        #pragma unroll
        for (int r = 0; r < 16; ++r) {
            int t = tid + r * 1024;
            float2 v = make_float2(0.f, 0.f);
            if (t < HALF) { v.x = ub[(size_t)(2 * t) * 64]; v.y = ub[(size_t)(2 * t + 1) * 64]; }
            A[t] = v;
        }
    }
    fft_dif(A, Tbl, tid);
    const float2* Kdd = Kd + (size_t)d * 2 * MF;
    float2 Wr[16];
    #pragma unroll
    for (int r = 0; r < 16; ++r) {
        int k = tid + r * 1024;
        float2 Zk = A[brev14(k)];
        float2 Zm = A[brev14((MF - k) & (MF - 1))];
        Zm.y = -Zm.y;
        float2 Ue = make_float2(0.5f*(Zk.x + Zm.x), 0.5f*(Zk.y + Zm.y));
        float2 dd = make_float2(Zk.x - Zm.x, Zk.y - Zm.y);
        float2 Uo = make_float2(0.5f*dd.y, -0.5f*dd.x);
        float kf = (float)k * (1.0f / (float)MF);
        float2 w = make_float2(cospif(kf), -sinpif(kf));
        float2 t2 = cmulf(w, Uo);
        float2 X0 = make_float2(Ue.x + t2.x, Ue.y + t2.y);
        float2 X1 = make_float2(Ue.x - t2.x, Ue.y - t2.y);
        float2 Y0 = cmulf(X0, Kdd[k]);
        float2 Y1 = cmulf(X1, Kdd[MF + k]);
        float2 Ey = make_float2(0.5f*(Y0.x + Y1.x), 0.5f*(Y0.y + Y1.y));
        float2 Dy = make_float2(Y0.x - Y1.x, Y0.y - Y1.y);
        float2 wc = make_float2(w.x, -w.y);
        float2 Oy = cmulf(wc, Dy);
        Oy.x *= 0.5f; Oy.y *= 0.5f;
        Wr[r] = make_float2(Ey.x - Oy.y, Ey.y + Oy.x);   // Z' = Ey + i*Oy
    }
    __syncthreads();
    #pragma unroll
    for (int r = 0; r < 16; ++r) { int k = tid + r * 1024; A[brev14(k)] = Wr[r]; }
    fft_dit_inv(A, Tbl, tid);
    const float s = 1.0f / (float)MF;
    if (TRANS) {
        float2* dst = (float2*)(yT + (size_t)bd * MF);
        #pragma unroll
        for (int r = 0; r < 8; ++r) {
            int t = tid + r * 1024;
            float2 v = A[t];
            dst[t] = make_float2(v.x * s, v.y * s);
        }
    } else {
        float Dd = Dp[d];
        float* yb = yout + ((size_t)b * MF) * 64 + d;
        const float* ub = u + ((size_t)b * MF) * 64 + d;
        #pragma unroll
        for (int r = 0; r < 8; ++r) {
            int t = tid + r * 1024;
            float2 v = A[t];
            yb[(size_t)(2 * t) * 64]     = v.x * s + Dd * ub[(size_t)(2 * t) * 64];
            yb[(size_t)(2 * t + 1) * 64] = v.y * s + Dd * ub[(size_t)(2 * t + 1) * 64];
        }
    }
}

// ---------------- output: y[b][t][d] = yT[b][d][t] + D[d]*u[b][t][d] ----------------
__global__ void k_out(const float* __restrict__ yT, const float* __restrict__ u,
                      const float* __restrict__ Dp, float* __restrict__ y) {
    __shared__ float tile[64][65];
    int b = blockIdx.y, t0 = blockIdx.x * 64, tid = threadIdx.x;
    #pragma unroll
    for (int k2 = 0; k2 < 16; ++k2) {
        int idx = tid + k2 * 256;
        int dl = idx >> 6, tl = idx & 63;
        tile[dl][tl] = yT[((size_t)b * 64 + dl) * MF + t0 + tl];
    }
    __syncthreads();
    #pragma unroll
    for (int k2 = 0; k2 < 16; ++k2) {
        int idx = tid + k2 * 256;
        int tl = idx >> 6, dl = idx & 63;
        size_t gi = ((size_t)(b * MF + t0 + tl)) * 64 + dl;
        y[gi] = tile[dl][tl] + Dp[dl] * u[gi];
    }
}

extern "C" void kernel_launch(void* const* d_in, const int* in_sizes, int n_in,
                              void* d_out, int out_size, void* d_ws, size_t ws_size,
                              hipStream_t stream) {
    const float*  u   = (const float*)d_in[0];
    const float2* Lam = (const float2*)d_in[1];
    const float2* P   = (const float2*)d_in[2];
    const float2* Bc  = (const float2*)d_in[3];
    const float2* C   = (const float2*)d_in[4];
    const float*  Dp  = (const float*)d_in[5];
    const float*  ls  = (const float*)d_in[6];
    float* y = (float*)d_out;
    char* ws = (char*)d_ws;

    size_t off = 0;
    float2* Tbl = (float2*)(ws + off); off += (size_t)HALF * sizeof(float2);          // 64 KB
    float2* E   = (float2*)(ws + off); off += (size_t)64 * MF * sizeof(float2);       // 8 MB
    float*  Kt  = (float*) (ws + off); off += (size_t)64 * MF * sizeof(float);        // 4 MB
    float2* Kd  = (float2*)(ws + off); off += (size_t)64 * 2 * MF * sizeof(float2);   // 16 MB
    size_t off_base = off;
    float*  uT  = (float*) (ws + off); off += (size_t)1024 * MF * sizeof(float);      // 64 MB
    float*  yT  = (float*) (ws + off); off += (size_t)1024 * MF * sizeof(float);      // 64 MB
    bool trans = (ws_size >= off);
    (void)off_base;

    k_twiddle<<<HALF / 256, 256, 0, stream>>>(Tbl);
    k_eval<<<(64 * MF) / 256, 256, 0, stream>>>(Lam, P, Bc, C, ls, E);
    k_ifft_E<<<64, 1024, 0, stream>>>(E, Kt, Tbl);
    k_fft_K<<<64, 1024, 0, stream>>>(Kt, Kd, Tbl);

    if (trans) {
        dim3 tg(MF / 64, 16);
        k_transpose_in<<<tg, 256, 0, stream>>>(u, uT);
        k_conv<true><<<1024, 1024, 0, stream>>>(u, uT, Kd, Dp, yT, y, Tbl);
        k_out<<<tg, 256, 0, stream>>>(yT, u, Dp, y);
    } else {
        k_conv<false><<<1024, 1024, 0, stream>>>(u, nullptr, Kd, Dp, nullptr, y, Tbl);
    }
}

// Round 2
// 394.499 us; speedup vs baseline: 1.9873x; 1.9873x over previous
//
#include <hip/hip_runtime.h>
#include <math.h>

#define MF 16384
#define HALF 8192
#define LOG2M 14
#define PH(i) ((i) ^ (((i) >> 3) & 15))

__device__ __forceinline__ float2 cmul(float2 a, float2 b) {
    return make_float2(a.x*b.x - a.y*b.y, a.x*b.y + a.y*b.x);
}
__device__ __forceinline__ float2 cmulc(float2 a, float2 b) {   // a * conj(b)
    return make_float2(a.x*b.x + a.y*b.y, a.y*b.x - a.x*b.y);
}
// base-4 digit reversal of 7 digits (14 bits)
__device__ __forceinline__ int d4rev(int s) {
    unsigned br = __brev((unsigned)s) >> 18;
    return (int)(((br & 0x2AAAu) >> 1) | ((br & 0x1555u) << 1));
}

// ---------------- per-stage twiddle tables: tws[st][m], st=0..6 ----------------
__global__ void k_twiddle4(float2* __restrict__ tws) {
    int id = blockIdx.x * 256 + threadIdx.x;
    if (id < 7 * 4096) {
        int st = id >> 12, m = id & 4095;
        int h = 4096 >> (2 * st);
        int j = m & (h - 1);
        double a = -2.0 * 3.14159265358979323846 * (double)j / (double)(4 * h);
        tws[id] = make_float2((float)cos(a), (float)sin(a));
    }
}

// ---------------- radix-4 DIF forward (natural in -> digit-reversed out) ----------------
__device__ void fft4_dif(float2* A, const float2* __restrict__ tws, int tid) {
    #pragma unroll
    for (int st = 0; st < 7; ++st) {
        int h = 4096 >> (2 * st);
        __syncthreads();
        #pragma unroll
        for (int r = 0; r < 4; ++r) {
            int m = tid + (r << 10);
            int j = m & (h - 1);
            int base = ((m ^ j) << 2) | j;
            int i0 = PH(base), i1 = PH(base + h), i2 = PH(base + 2*h), i3 = PH(base + 3*h);
            float2 x0 = A[i0], x1 = A[i1], x2 = A[i2], x3 = A[i3];
            float2 w1 = tws[(st << 12) + m];
            float2 w2 = cmul(w1, w1);
            float2 w3 = cmul(w2, w1);
            float2 t0 = make_float2(x0.x + x2.x, x0.y + x2.y);
            float2 t1 = make_float2(x1.x + x3.x, x1.y + x3.y);
            float2 t2 = make_float2(x0.x - x2.x, x0.y - x2.y);
            float2 t3 = make_float2(x1.x - x3.x, x1.y - x3.y);
            float2 y1 = make_float2(t2.x + t3.y, t2.y - t3.x);   // t2 - i*t3
            float2 y3 = make_float2(t2.x - t3.y, t2.y + t3.x);   // t2 + i*t3
            A[i0] = make_float2(t0.x + t1.x, t0.y + t1.y);
            A[i1] = cmul(y1, w1);
            A[i2] = cmul(make_float2(t0.x - t1.x, t0.y - t1.y), w2);
            A[i3] = cmul(y3, w3);
        }
    }
}

// ---------------- radix-4 DIT inverse (digit-reversed in -> natural out, unscaled) ----------------
__device__ void fft4_dit_inv(float2* A, const float2* __restrict__ tws, int tid) {
    #pragma unroll
    for (int st = 6; st >= 0; --st) {
        int h = 4096 >> (2 * st);
        __syncthreads();
        #pragma unroll
        for (int r = 0; r < 4; ++r) {
            int m = tid + (r << 10);
            int j = m & (h - 1);
            int base = ((m ^ j) << 2) | j;
            int i0 = PH(base), i1 = PH(base + h), i2 = PH(base + 2*h), i3 = PH(base + 3*h);
            float2 x0 = A[i0], x1 = A[i1], x2 = A[i2], x3 = A[i3];
            float2 w1 = tws[(st << 12) + m];
            float2 w2 = cmul(w1, w1);
            float2 w3 = cmul(w2, w1);
            float2 u1 = cmulc(x1, w1), u2 = cmulc(x2, w2), u3 = cmulc(x3, w3);
            float2 t0 = make_float2(x0.x + u2.x, x0.y + u2.y);
            float2 t1 = make_float2(u1.x + u3.x, u1.y + u3.y);
            float2 t2 = make_float2(x0.x - u2.x, x0.y - u2.y);
            float2 t3 = make_float2(u1.x - u3.x, u1.y - u3.y);
            A[i0] = make_float2(t0.x + t1.x, t0.y + t1.y);
            A[i1] = make_float2(t2.x - t3.y, t2.y + t3.x);   // t2 + i*t3
            A[i2] = make_float2(t0.x - t1.x, t0.y - t1.y);
            A[i3] = make_float2(t2.x + t3.y, t2.y - t3.x);   // t2 - i*t3
        }
    }
}

// ---------------- evaluate generating function (f32, stable form), E[d][l] ----------------
// 2/(1+Om) * 1/(g - lam) == 2*step/denom,  denom = 2(1-Om) - step*lam*(1+Om)
__global__ __launch_bounds__(1024) void k_eval(const float2* __restrict__ Lam, const float2* __restrict__ P,
                                               const float2* __restrict__ Bc, const float2* __restrict__ C,
                                               const float* __restrict__ log_step, float2* __restrict__ E) {
    __shared__ float2 bTs[16][64];
    __shared__ float2 pTs[16][64];
    __shared__ float2 S10s[16], S11s[16];
    __shared__ float2 C_l[64][65];     // [n][d]
    __shared__ float2 tile[16][65];    // [l_local][d]
    int tid = threadIdx.x;
    int l0 = blockIdx.x * 64;
    float step = expf(log_step[0]);
    // stage C (transposed): C_l[n][d] = C[d][n]
    {
        int dq = tid >> 6, n = tid & 63;
        #pragma unroll
        for (int p = 0; p < 4; ++p) {
            int dd = dq + p * 16;
            C_l[n][dd] = C[dd * 64 + n];
        }
    }
    __syncthreads();
    int w = tid >> 6;       // wave index 0..15
    int lane = tid & 63;
    for (int p = 0; p < 4; ++p) {
        int li = p * 16 + w;
        int l = l0 + li;
        float lf = (float)l * (1.0f / 16384.0f);
        float s2 = sinpif(lf), c2 = cospif(lf);
        float2 q1 = make_float2(2.0f*c2*c2, -2.0f*s2*c2);   // 1+Om
        {   // phase A: lane = n
            int n = lane;
            float2 q2 = make_float2(4.0f*s2*s2, 4.0f*s2*c2); // 2(1-Om)
            float2 ln = Lam[n];
            float2 lq = cmul(ln, q1);
            float2 den = make_float2(q2.x - step*lq.x, q2.y - step*lq.y);
            float idn = step / (den.x*den.x + den.y*den.y);
            float2 T = make_float2(den.x*idn, -den.y*idn);
            float2 bn = Bc[n], pn = P[n];
            float2 bT = cmul(bn, T), pT = cmul(pn, T);
            bTs[w][n] = bT; pTs[w][n] = pT;
            float2 s10 = make_float2(pn.x*bT.x + pn.y*bT.y, pn.x*bT.y - pn.y*bT.x); // conj(P)*bT
            float2 s11 = make_float2(pn.x*pT.x + pn.y*pT.y, pn.x*pT.y - pn.y*pT.x);
            #pragma unroll
            for (int off = 32; off > 0; off >>= 1) {
                s10.x += __shfl_xor(s10.x, off);
                s10.y += __shfl_xor(s10.y, off);
                s11.x += __shfl_xor(s11.x, off);
                s11.y += __shfl_xor(s11.y, off);
            }
            if (n == 0) { S10s[w] = s10; S11s[w] = s11; }
        }
        __syncthreads();
        {   // phase B: lane = d
            int d = lane;
            float2 S00 = make_float2(0.f, 0.f), S01 = make_float2(0.f, 0.f);
            #pragma unroll 8
            for (int n = 0; n < 64; ++n) {
                float2 cn = C_l[n][d];
                float2 bT = bTs[w][n];
                float2 pT = pTs[w][n];
                S00.x += cn.x*bT.x + cn.y*bT.y;  S00.y += cn.x*bT.y - cn.y*bT.x;  // conj(C)*bT
                S01.x += cn.x*pT.x + cn.y*pT.y;  S01.y += cn.x*pT.y - cn.y*pT.x;
            }
            float2 S10 = S10s[w], S11 = S11s[w];
            float2 k11 = cmul(q1, S11); k11.x += 1.0f;
            float2 k10q = cmul(q1, S10);
            float ik = 1.0f / (k11.x*k11.x + k11.y*k11.y);
            float2 quo = make_float2((k10q.x*k11.x + k10q.y*k11.y) * ik,
                                     (k10q.y*k11.x - k10q.x*k11.y) * ik);
            float2 corr = cmul(S01, quo);
            tile[w][d] = make_float2(2.0f*(S00.x - corr.x), 2.0f*(S00.y - corr.y));
        }
        __syncthreads();
        {   // write out, coalesced in 128B segments
            int lo = tid & 15, dq = tid >> 4;
            E[(size_t)dq * MF + l0 + p * 16 + lo] = tile[lo][dq];
        }
        __syncthreads();
    }
}

// ---------------- K time domain: Kt[d][t] = Re(ifft(E[d])) ----------------
__global__ __launch_bounds__(1024) void k_ifft_E(const float2* __restrict__ E, float* __restrict__ Kt,
                                                 const float2* __restrict__ tws) {
    __shared__ float2 A[MF];
    int d = blockIdx.x, tid = threadIdx.x;
    const float2* Ed = E + (size_t)d * MF;
    #pragma unroll
    for (int r = 0; r < 16; ++r) { int l = tid + (r << 10); A[PH(d4rev(l))] = Ed[l]; }
    fft4_dit_inv(A, tws, tid);
    __syncthreads();
    const float s = 1.0f / (float)MF;
    float* Ktd = Kt + (size_t)d * MF;
    #pragma unroll
    for (int r = 0; r < 16; ++r) { int t = tid + (r << 10); Ktd[t] = A[PH(t)].x * s; }
}

// ---------------- Kd in dr-slot layout: KdA[d][s]=Kd[k(s)], KdB[d][s]=Kd[MF+k(s)] ----------------
__global__ __launch_bounds__(1024) void k_fft_K(const float* __restrict__ Kt, float2* __restrict__ KdA,
                                                float2* __restrict__ KdB, const float2* __restrict__ tws) {
    __shared__ float2 A[MF];
    int d = blockIdx.x, tid = threadIdx.x;
    const float2* src = (const float2*)(Kt + (size_t)d * MF);
    #pragma unroll
    for (int r = 0; r < 16; ++r) {
        int t = tid + (r << 10);
        A[PH(t)] = (t < HALF) ? src[t] : make_float2(0.f, 0.f);
    }
    fft4_dif(A, tws, tid);
    __syncthreads();
    #pragma unroll
    for (int r = 0; r < 16; ++r) {
        int s = tid + (r << 10);
        int k = d4rev(s);
        int s2 = d4rev((MF - k) & (MF - 1));
        float2 Zk = A[PH(s)];
        float2 Zm = A[PH(s2)]; Zm.y = -Zm.y;
        float2 Ue = make_float2(0.5f*(Zk.x + Zm.x), 0.5f*(Zk.y + Zm.y));
        float2 dd = make_float2(Zk.x - Zm.x, Zk.y - Zm.y);
        float2 Uo = make_float2(0.5f*dd.y, -0.5f*dd.x);
        float kf = (float)k * (1.0f / (float)MF);
        float2 w = make_float2(cospif(kf), -sinpif(kf));
        float2 t2 = cmul(w, Uo);
        KdA[(size_t)d * MF + s] = make_float2(Ue.x + t2.x, Ue.y + t2.y);
        KdB[(size_t)d * MF + s] = make_float2(Ue.x - t2.x, Ue.y - t2.y);
    }
}

// ---------------- transpose u (B,L,D) -> uT (B,D,L) ----------------
__global__ void k_transpose_in(const float* __restrict__ u, float* __restrict__ uT) {
    __shared__ float tile[64][65];
    int b = blockIdx.y, t0 = blockIdx.x * 64, tid = threadIdx.x;
    #pragma unroll
    for (int k2 = 0; k2 < 16; ++k2) {
        int idx = tid + k2 * 256;
        int tl = idx >> 6, dl = idx & 63;
        tile[tl][dl] = u[((size_t)(b * MF + t0 + tl)) * 64 + dl];
    }
    __syncthreads();
    #pragma unroll
    for (int k2 = 0; k2 < 16; ++k2) {
        int idx = tid + k2 * 256;
        int dl = idx >> 6, tl = idx & 63;
        uT[((size_t)b * 64 + dl) * MF + t0 + tl] = tile[tl][dl];
    }
}

// ---------------- main conv: per (b,d) one 16384-pt packed-real FFT conv ----------------
template<bool TRANS>
__global__ __launch_bounds__(1024) void k_conv(const float* __restrict__ u, const float* __restrict__ uT,
                                               const float2* __restrict__ KdA, const float2* __restrict__ KdB,
                                               const float* __restrict__ Dp,
                                               float* __restrict__ yT, float* __restrict__ yout,
                                               const float2* __restrict__ tws) {
    __shared__ float2 A[MF];
    int bd = blockIdx.x, tid = threadIdx.x;
    int b = bd >> 6, d = bd & 63;
    if (TRANS) {
        const float2* src = (const float2*)(uT + (size_t)bd * MF);
        #pragma unroll
        for (int r = 0; r < 16; ++r) {
            int t = tid + (r << 10);
            A[PH(t)] = (t < HALF) ? src[t] : make_float2(0.f, 0.f);
        }
    } else {
        const float* ub = u + ((size_t)b * MF) * 64 + d;
        #pragma unroll
        for (int r = 0; r < 16; ++r) {
            int t = tid + (r << 10);
            float2 v = make_float2(0.f, 0.f);
            if (t < HALF) { v.x = ub[(size_t)(2 * t) * 64]; v.y = ub[(size_t)(2 * t + 1) * 64]; }
            A[PH(t)] = v;
        }
    }
    fft4_dif(A, tws, tid);
    __syncthreads();
    const float2* KdAd = KdA + (size_t)d * MF;
    const float2* KdBd = KdB + (size_t)d * MF;
    float2 Wr[16];
    #pragma unroll
    for (int r = 0; r < 16; ++r) {
        int s = tid + (r << 10);
        int k = d4rev(s);
        int s2 = d4rev((MF - k) & (MF - 1));
        float2 Zk = A[PH(s)];
        float2 Zm = A[PH(s2)]; Zm.y = -Zm.y;
        float2 Ue = make_float2(0.5f*(Zk.x + Zm.x), 0.5f*(Zk.y + Zm.y));
        float2 dd = make_float2(Zk.x - Zm.x, Zk.y - Zm.y);
        float2 Uo = make_float2(0.5f*dd.y, -0.5f*dd.x);
        float kf = (float)k * (1.0f / (float)MF);
        float2 w = make_float2(cospif(kf), -sinpif(kf));
        float2 t2 = cmul(w, Uo);
        float2 X0 = make_float2(Ue.x + t2.x, Ue.y + t2.y);
        float2 X1 = make_float2(Ue.x - t2.x, Ue.y - t2.y);
        float2 Y0 = cmul(X0, KdAd[s]);
        float2 Y1 = cmul(X1, KdBd[s]);
        float2 Ey = make_float2(0.5f*(Y0.x + Y1.x), 0.5f*(Y0.y + Y1.y));
        float2 Dy = make_float2(Y0.x - Y1.x, Y0.y - Y1.y);
        float2 wc = make_float2(w.x, -w.y);
        float2 Oy = cmul(wc, Dy);
        Oy.x *= 0.5f; Oy.y *= 0.5f;
        Wr[r] = make_float2(Ey.x - Oy.y, Ey.y + Oy.x);   // Z' = Ey + i*Oy
    }
    __syncthreads();
    #pragma unroll
    for (int r = 0; r < 16; ++r) { int s = tid + (r << 10); A[PH(s)] = Wr[r]; }
    fft4_dit_inv(A, tws, tid);
    __syncthreads();
    const float sc = 1.0f / (float)MF;
    if (TRANS) {
        float2* dst = (float2*)(yT + (size_t)bd * MF);
        #pragma unroll
        for (int r = 0; r < 8; ++r) {
            int t = tid + (r << 10);
            float2 v = A[PH(t)];
            dst[t] = make_float2(v.x * sc, v.y * sc);
        }
    } else {
        float Dd = Dp[d];
        float* yb = yout + ((size_t)b * MF) * 64 + d;
        const float* ub = u + ((size_t)b * MF) * 64 + d;
        #pragma unroll
        for (int r = 0; r < 8; ++r) {
            int t = tid + (r << 10);
            float2 v = A[PH(t)];
            yb[(size_t)(2 * t) * 64]     = v.x * sc + Dd * ub[(size_t)(2 * t) * 64];
            yb[(size_t)(2 * t + 1) * 64] = v.y * sc + Dd * ub[(size_t)(2 * t + 1) * 64];
        }
    }
}

// ---------------- output: y[b][t][d] = yT[b][d][t] + D[d]*u[b][t][d] ----------------
__global__ void k_out(const float* __restrict__ yT, const float* __restrict__ u,
                      const float* __restrict__ Dp, float* __restrict__ y) {
    __shared__ float tile[64][65];
    int b = blockIdx.y, t0 = blockIdx.x * 64, tid = threadIdx.x;
    #pragma unroll
    for (int k2 = 0; k2 < 16; ++k2) {
        int idx = tid + k2 * 256;
        int dl = idx >> 6, tl = idx & 63;
        tile[dl][tl] = yT[((size_t)b * 64 + dl) * MF + t0 + tl];
    }
    __syncthreads();
    #pragma unroll
    for (int k2 = 0; k2 < 16; ++k2) {
        int idx = tid + k2 * 256;
        int tl = idx >> 6, dl = idx & 63;
        size_t gi = ((size_t)(b * MF + t0 + tl)) * 64 + dl;
        y[gi] = tile[dl][tl] + Dp[dl] * u[gi];
    }
}

extern "C" void kernel_launch(void* const* d_in, const int* in_sizes, int n_in,
                              void* d_out, int out_size, void* d_ws, size_t ws_size,
                              hipStream_t stream) {
    const float*  u   = (const float*)d_in[0];
    const float2* Lam = (const float2*)d_in[1];
    const float2* P   = (const float2*)d_in[2];
    const float2* Bc  = (const float2*)d_in[3];
    const float2* C   = (const float2*)d_in[4];
    const float*  Dp  = (const float*)d_in[5];
    const float*  ls  = (const float*)d_in[6];
    float* y = (float*)d_out;
    char* ws = (char*)d_ws;

    size_t off = 0;
    float2* tws = (float2*)(ws + off); off += (size_t)7 * 4096 * sizeof(float2);      // 229 KB
    float2* E   = (float2*)(ws + off); off += (size_t)64 * MF * sizeof(float2);       // 8 MB
    float*  Kt  = (float*) (ws + off); off += (size_t)64 * MF * sizeof(float);        // 4 MB
    float2* KdA = (float2*)(ws + off); off += (size_t)64 * MF * sizeof(float2);       // 8 MB
    float2* KdB = (float2*)(ws + off); off += (size_t)64 * MF * sizeof(float2);       // 8 MB
    float*  uT  = (float*) (ws + off); off += (size_t)1024 * MF * sizeof(float);      // 64 MB
    float*  yT  = (float*) (ws + off); off += (size_t)1024 * MF * sizeof(float);      // 64 MB
    bool trans = (ws_size >= off);

    k_twiddle4<<<(7 * 4096 + 255) / 256, 256, 0, stream>>>(tws);
    k_eval<<<256, 1024, 0, stream>>>(Lam, P, Bc, C, ls, E);
    k_ifft_E<<<64, 1024, 0, stream>>>(E, Kt, tws);
    k_fft_K<<<64, 1024, 0, stream>>>(Kt, KdA, KdB, tws);

    if (trans) {
        dim3 tg(MF / 64, 16);
        k_transpose_in<<<tg, 256, 0, stream>>>(u, uT);
        k_conv<true><<<1024, 1024, 0, stream>>>(u, uT, KdA, KdB, Dp, yT, y, tws);
        k_out<<<tg, 256, 0, stream>>>(yT, u, Dp, y);
    } else {
        k_conv<false><<<1024, 1024, 0, stream>>>(u, nullptr, KdA, KdB, Dp, nullptr, y, tws);
    }
}